// Round 10
// baseline (4997.111 us; speedup 1.0000x reference)
//
#include <hip/hip_runtime.h>
#include <cstdint>
#include <cstddef>

#define B_    256
#define Q_    512
#define D_    32
#define H_    192
#define HID_  384
#define INCH_ 96
#define M_    (B_*Q_)    // 131072
#define WOUT_ 64
#define BPB   2          // batches per rollout block (2 -> 128 blocks)
#define RT_   384        // rollout threads (split-K 2-way over 192 outputs)
#define PI_F  3.14159265358979323846f

typedef unsigned int uint_t;

__device__ __forceinline__ float sigm(float x){ return 1.f/(1.f+expf(-x)); }
__device__ __forceinline__ float gelu_exact(float x){ return 0.5f*x*(1.f+erff(x*0.7071067811865475f)); }

// ---------------- features: [x, dy, ddy] ----------------
__global__ void feats_kernel(const float* __restrict__ x, float* __restrict__ feats, int nrows){
  int idx = blockIdx.x*256 + threadIdx.x;
  if (idx >= nrows*32) return;
  int d  = idx & 31;
  int bt = idx >> 5;
  int t  = bt & 511;
  const float* xr = x + (size_t)bt*D_;
  float xc  = xr[d];
  float xm1 = (t>0) ? xr[d - D_]   : 0.f;
  float xm2 = (t>1) ? xr[d - 2*D_] : 0.f;
  float dy   = (t>0) ? xc - xm1   : 0.f;
  float dym1 = (t>1) ? xm1 - xm2  : 0.f;
  float ddy  = (t>0) ? dy - dym1  : 0.f;
  float* fr = feats + (size_t)bt*INCH_;
  fr[d] = xc; fr[D_+d] = dy; fr[2*D_+d] = ddy;
}

// ---------------- 64x64x8 fp32 tiled GEMM, 4 blocks/CU ----------------
// MODE 0: out = acc+bias ; MODE 1: out = gelu(acc+bias) ; MODE 2: A affine, C += acc+bias
template<int MODE>
__global__ __launch_bounds__(256,4) void gemm_t64(
    const float* __restrict__ Af,
    const float* __restrict__ W,  const float* __restrict__ bias,
    float* __restrict__ Cf,
    const float* __restrict__ scale, const float* __restrict__ grnb,
    int N, int K)
{
  __shared__ float As[8][64];
  __shared__ float Bs[8][64];
  const int tid = threadIdx.x;
  const int bm = blockIdx.x*64, bn = blockIdx.y*64;
  const int tx = tid & 15, ty = tid >> 4;
  const int lrow = (tid & 127) >> 1, lk = (tid & 1)*4;
  const bool isA = tid < 128;
  const float* srow = (MODE==2) ? (scale + (size_t)(bm>>9)*HID_) : nullptr;

  float acc[4][4];
  #pragma unroll
  for (int i=0;i<4;i++)
    #pragma unroll
    for (int j=0;j<4;j++) acc[i][j]=0.f;

  const float* gsrc = isA ? (Af + (size_t)(bm+lrow)*K) : (W + (size_t)(bn+lrow)*K);

  for (int k0=0;k0<K;k0+=8){
    float4 v = *(const float4*)(gsrc + k0 + lk);
    if (MODE==2 && isA){
      int c = k0+lk;
      float4 sc = *(const float4*)(srow+c);
      float4 gb = *(const float4*)(grnb+c);
      v.x = v.x*sc.x+gb.x; v.y = v.y*sc.y+gb.y;
      v.z = v.z*sc.z+gb.z; v.w = v.w*sc.w+gb.w;
    }
    if (isA){
      As[lk+0][lrow]=v.x; As[lk+1][lrow]=v.y; As[lk+2][lrow]=v.z; As[lk+3][lrow]=v.w;
    } else {
      Bs[lk+0][lrow]=v.x; Bs[lk+1][lrow]=v.y; Bs[lk+2][lrow]=v.z; Bs[lk+3][lrow]=v.w;
    }
    __syncthreads();
    #pragma unroll
    for (int kk=0;kk<8;kk++){
      float4 a = *(const float4*)&As[kk][ty*4];
      float4 b = *(const float4*)&Bs[kk][tx*4];
      float ar[4] = {a.x,a.y,a.z,a.w};
      #pragma unroll
      for (int i=0;i<4;i++){
        acc[i][0] += ar[i]*b.x; acc[i][1] += ar[i]*b.y;
        acc[i][2] += ar[i]*b.z; acc[i][3] += ar[i]*b.w;
      }
    }
    __syncthreads();
  }

  const int o0 = bn + tx*4;
  float4 b0 = *(const float4*)(bias + o0);
  #pragma unroll
  for (int i=0;i<4;i++){
    int m = bm + ty*4 + i;
    if (MODE==0){
      float4 v; v.x=acc[i][0]+b0.x; v.y=acc[i][1]+b0.y; v.z=acc[i][2]+b0.z; v.w=acc[i][3]+b0.w;
      *(float4*)(Cf + (size_t)m*N + o0) = v;
    } else if (MODE==1){
      float4 v;
      v.x = gelu_exact(acc[i][0]+b0.x); v.y = gelu_exact(acc[i][1]+b0.y);
      v.z = gelu_exact(acc[i][2]+b0.z); v.w = gelu_exact(acc[i][3]+b0.w);
      *(float4*)(Cf + (size_t)m*N + o0) = v;
    } else {
      float4 old = *(const float4*)(Cf + (size_t)m*N + o0);
      float4 v; v.x=old.x+acc[i][0]+b0.x; v.y=old.y+acc[i][1]+b0.y;
      v.z=old.z+acc[i][2]+b0.z; v.w=old.w+acc[i][3]+b0.w;
      *(float4*)(Cf + (size_t)m*N + o0) = v;
    }
  }
}

// ---------------- depthwise conv (k=9, edge pad) + LN, 4 timesteps per block ----------------
__global__ __launch_bounds__(192) void dwconv_ln4(
  const float* __restrict__ h, const float* __restrict__ dww, const float* __restrict__ dwb,
  const float* __restrict__ lnw, const float* __restrict__ lnb, float* __restrict__ yln)
{
  __shared__ float sh[12][192];
  __shared__ float rs_[192], rq_[192], st[2];
  const int c  = threadIdx.x;
  const int t0 = (blockIdx.x & 127) * 4;
  const size_t base = (size_t)(blockIdx.x >> 7) * Q_ * H_;
  #pragma unroll
  for (int r=0;r<12;r++){
    int tt = t0 - 4 + r; tt = tt<0?0:(tt>511?511:tt);
    sh[r][c] = h[base + (size_t)tt*H_ + c];
  }
  float w[9];
  #pragma unroll
  for (int k=0;k<9;k++) w[k] = dww[c*9+k];
  const float dbias = dwb[c], lw = lnw[c], lb = lnb[c];
  __syncthreads();
  for (int i=0;i<4;i++){
    float acc = dbias;
    #pragma unroll
    for (int k=0;k<9;k++) acc += w[k]*sh[i+k][c];
    rs_[c]=acc; rq_[c]=acc*acc;
    __syncthreads();
    if (c < 64){
      float s = rs_[c]+rs_[c+64]+rs_[c+128];
      float q = rq_[c]+rq_[c+64]+rq_[c+128];
      #pragma unroll
      for (int off=32; off>0; off>>=1){ s += __shfl_down(s,off); q += __shfl_down(q,off); }
      if (c==0){ st[0]=s; st[1]=q; }
    }
    __syncthreads();
    float mean = st[0]*(1.f/H_);
    float var  = st[1]*(1.f/H_) - mean*mean;
    float r = rsqrtf(var + 1e-5f);
    yln[base + (size_t)(t0+i)*H_ + c] = (acc-mean)*r*lw + lb;
  }
}

// ---------------- output LayerNorm (+ save last-timestep row) ----------------
__global__ __launch_bounds__(192) void out_ln_kernel(
  const float* __restrict__ h, const float* __restrict__ lnw, const float* __restrict__ lnb,
  float* __restrict__ o, float* __restrict__ hlast, int b0)
{
  __shared__ float rs_[192], rq_[192], st[2];
  const int c  = threadIdx.x;
  const int bt = blockIdx.x;
  float v = h[(size_t)bt*H_ + c];
  rs_[c]=v; rq_[c]=v*v;
  __syncthreads();
  if (c < 64){
    float s = rs_[c]+rs_[c+64]+rs_[c+128];
    float q = rq_[c]+rq_[c+64]+rq_[c+128];
    #pragma unroll
    for (int off=32; off>0; off>>=1){ s += __shfl_down(s,off); q += __shfl_down(q,off); }
    if (c==0){ st[0]=s; st[1]=q; }
  }
  __syncthreads();
  float mean = st[0]*(1.f/H_);
  float var  = st[1]*(1.f/H_) - mean*mean;
  float r = rsqrtf(var + 1e-5f);
  float res = (v-mean)*r*lnw[c] + lnb[c];
  o[(size_t)bt*H_ + c] = res;
  if ((bt & 511) == 511) hlast[(size_t)(b0 + (bt>>9))*H_ + c] = res;
}

// ---------------- GRN stats ----------------
__global__ __launch_bounds__(384) void grn_stats_kernel(
  const float* __restrict__ y1, const float* __restrict__ grn_g, float* __restrict__ scale)
{
  __shared__ float r[384];
  const int c = threadIdx.x;
  const int b = blockIdx.x;
  const float* p = y1 + (size_t)b*Q_*HID_ + c;
  float s = 0.f;
  #pragma unroll 8
  for (int t=0;t<Q_;t++){ float v = p[(size_t)t*HID_]; s += v*v; }
  float gx = sqrtf(s);
  r[c] = gx;
  __syncthreads();
  if (c < 64){
    float v = r[c]+r[c+64]+r[c+128]+r[c+192]+r[c+256]+r[c+320];
    #pragma unroll
    for (int off=32; off>0; off>>=1) v += __shfl_down(v,off);
    if (c==0) r[0]=v;
  }
  __syncthreads();
  float mean = r[0]*(1.f/HID_);
  scale[(size_t)b*HID_ + c] = 1.f + grn_g[c]*gx/(mean + 1e-6f);
}

// ---------------- pack fc_rp / fc_gain into padded (64,192) W ----------------
__global__ void pack_w_kernel(const float* __restrict__ frw, const float* __restrict__ frb,
                              const float* __restrict__ fgw, const float* __restrict__ fgb,
                              float* __restrict__ w_pad, float* __restrict__ b_pad)
{
  int idx = blockIdx.x*256 + threadIdx.x;
  if (idx >= 64*192) return;
  int o = idx / 192, k = idx % 192;
  float v = 0.f;
  if (o < 2) v = frw[o*192+k]; else if (o < 34) v = fgw[(o-2)*192+k];
  w_pad[idx] = v;
  if (k == 0){
    float bv = 0.f;
    if (o < 2) bv = frb[o]; else if (o < 34) bv = fgb[o-2];
    b_pad[o] = bv;
  }
}

// ---------------- wide Kalman prep: raw (Mc,64) -> rp4 (Mc,16) float4 {rc,rs,g0,g1} ----------------
__global__ void kalman_prep_kernel(const float* __restrict__ raw, float* __restrict__ rp4, int nrows){
  int idx = blockIdx.x*256 + threadIdx.x;
  if (idx >= nrows*16) return;
  int m  = idx & 15;
  int bt = idx >> 4;
  const float* r = raw + (size_t)bt*64;
  float rho = 1.25f*sigm(r[0]);
  float phi = PI_F * tanhf(r[1]);
  float4 v;
  v.x = rho*cosf(phi);
  v.y = rho*sinf(phi);
  v.z = sigm(r[2+m]);
  v.w = sigm(r[18+m]);
  *(float4*)(rp4 + (size_t)idx*4) = v;
}

// ---------------- sequential Kalman scan — 4-t register blocks, loads batched ----------------
__global__ __launch_bounds__(64) void kalman_scan_kernel(
  const float* __restrict__ x_c, const float* __restrict__ rp4, float* __restrict__ xpost,
  int b0, int Bc)
{
  const int lane = threadIdx.x;
  const int bl = blockIdx.x*4 + (lane>>4);
  if (bl >= Bc) return;
  const int m = lane & 15;
  const float* xb = x_c + (size_t)bl*Q_*D_;
  const float4* rb = (const float4*)rp4 + (size_t)bl*Q_*16 + m;
  float re = xb[m], im = xb[16+m];
  for (int t=0;t<Q_;t+=4){
    float4 w0 = rb[(size_t)(t+0)*16];
    float4 w1 = rb[(size_t)(t+1)*16];
    float4 w2 = rb[(size_t)(t+2)*16];
    float4 w3 = rb[(size_t)(t+3)*16];
    float y00 = xb[(size_t)(t+0)*D_ + m], y01 = xb[(size_t)(t+0)*D_ + 16 + m];
    float y10 = xb[(size_t)(t+1)*D_ + m], y11 = xb[(size_t)(t+1)*D_ + 16 + m];
    float y20 = xb[(size_t)(t+2)*D_ + m], y21 = xb[(size_t)(t+2)*D_ + 16 + m];
    float y30 = xb[(size_t)(t+3)*D_ + m], y31 = xb[(size_t)(t+3)*D_ + 16 + m];
    float pr, pi;
    pr = w0.x*re - w0.y*im; pi = w0.y*re + w0.x*im;
    re = pr + w0.z*(y00 - pr); im = pi + w0.w*(y01 - pi);
    pr = w1.x*re - w1.y*im; pi = w1.y*re + w1.x*im;
    re = pr + w1.z*(y10 - pr); im = pi + w1.w*(y11 - pi);
    pr = w2.x*re - w2.y*im; pi = w2.y*re + w2.x*im;
    re = pr + w2.z*(y20 - pr); im = pi + w2.w*(y21 - pi);
    pr = w3.x*re - w3.y*im; pi = w3.y*re + w3.x*im;
    re = pr + w3.z*(y30 - pr); im = pi + w3.w*(y31 - pi);
  }
  xpost[(b0+bl)*D_ + m] = re;
  xpost[(b0+bl)*D_ + 16 + m] = im;
}

// ---------------- rollout weight prep: wT1[k][o] + packed [k][o][8] gate block ----------------
__global__ void prep_rollout_kernel(const float* __restrict__ riw, const float* __restrict__ wih,
                                    const float* __restrict__ whh,
                                    float* __restrict__ wT1, float* __restrict__ wPack)
{
  int idx = blockIdx.x*256 + threadIdx.x;
  if (idx < 224*192){
    int o = idx % 192, k = idx / 192;
    wT1[idx] = riw[o*224 + k];
    return;
  }
  idx -= 224*192;
  if (idx < 192*192){
    int o = idx % 192, k = idx / 192;
    float* w = wPack + ((size_t)k*192 + o)*8;
    w[0] = wih[(0*192+o)*192 + k];
    w[1] = wih[(1*192+o)*192 + k];
    w[2] = wih[(2*192+o)*192 + k];
    w[3] = whh[(0*192+o)*192 + k];
    w[4] = whh[(1*192+o)*192 + k];
    w[5] = whh[(2*192+o)*192 + k];
    w[6] = 0.f; w[7] = 0.f;
  }
}

// ---------------- GRU rollout: BPB=2 batches/block (128 blocks), 384 thr split-K,
// ---------------- 4-k register-blocked loads (32 live VGPRs of weights — spill-free) ----------------
__global__ __launch_bounds__(RT_, 1) void rollout_kernel(
  const float* __restrict__ hlast, const float* __restrict__ xpost,
  const float* __restrict__ wT1,  const float* __restrict__ rib_,
  const float* __restrict__ wPack,
  const float* __restrict__ bih,  const float* __restrict__ bhh,
  const float* __restrict__ lnw,  const float* __restrict__ lnb,
  const float* __restrict__ frw,  const float* __restrict__ frb,
  float* __restrict__ out)
{
  const int tid  = threadIdx.x;
  const int half = (tid >= 192) ? 1 : 0;   // wave-aligned split (192 = 3 waves)
  const int o    = tid - half*192;
  const int bb   = blockIdx.x*BPB;
  __shared__ float h[BPB][192], x[BPB][192], c[BPB][32];
  __shared__ float pA[192][BPB+1];
  __shared__ float pB[192][13];
  __shared__ float red1[BPB][192], red2[BPB][192];
  __shared__ float stL[BPB][2], stR[BPB][2];

  if (half==0){
    #pragma unroll
    for (int j=0;j<BPB;j++) h[j][o] = hlast[(size_t)(bb+j)*H_ + o];
  }
  if (tid < 32){
    #pragma unroll
    for (int j=0;j<BPB;j++) c[j][tid] = xpost[(bb+j)*D_ + tid];
  }
  const float w_ln = lnw[o], b_ln = lnb[o];
  const float w_r0 = frw[o], w_r1 = frw[192+o];
  const float fb0 = frb[0], fb1 = frb[1];
  const float bi0 = bih[o], bi1 = bih[192+o], bi2 = bih[384+o];
  const float bh0 = bhh[o], bh1 = bhh[192+o], bh2 = bhh[384+o];
  const float rib = rib_[o];
  __syncthreads();

  for (int s=0; s<WOUT_; s++){
    // ---- phase A: x = tanh(W1 @ [h; c] + b1), K split 0..111 / 112..223 ----
    float a[BPB];
    if (half==0){
      #pragma unroll
      for (int j=0;j<BPB;j++) a[j] = rib;
      for (int kg=0; kg<112; kg+=8){
        float w[8];
        #pragma unroll
        for (int u=0;u<8;u++) w[u] = wT1[(kg+u)*192+o];
        #pragma unroll
        for (int u=0;u<8;u+=4){
          #pragma unroll
          for (int j=0;j<BPB;j++){
            float4 hv = *(const float4*)&h[j][kg+u];
            a[j] += w[u]*hv.x + w[u+1]*hv.y + w[u+2]*hv.z + w[u+3]*hv.w;
          }
        }
      }
    } else {
      #pragma unroll
      for (int j=0;j<BPB;j++) a[j] = 0.f;
      for (int kg=112; kg<192; kg+=8){
        float w[8];
        #pragma unroll
        for (int u=0;u<8;u++) w[u] = wT1[(kg+u)*192+o];
        #pragma unroll
        for (int u=0;u<8;u+=4){
          #pragma unroll
          for (int j=0;j<BPB;j++){
            float4 hv = *(const float4*)&h[j][kg+u];
            a[j] += w[u]*hv.x + w[u+1]*hv.y + w[u+2]*hv.z + w[u+3]*hv.w;
          }
        }
      }
      for (int kg=0; kg<32; kg+=8){
        float w[8];
        #pragma unroll
        for (int u=0;u<8;u++) w[u] = wT1[(192+kg+u)*192+o];
        #pragma unroll
        for (int u=0;u<8;u+=4){
          #pragma unroll
          for (int j=0;j<BPB;j++){
            float4 cv = *(const float4*)&c[j][kg+u];
            a[j] += w[u]*cv.x + w[u+1]*cv.y + w[u+2]*cv.z + w[u+3]*cv.w;
          }
        }
      }
      #pragma unroll
      for (int j=0;j<BPB;j++) pA[o][j] = a[j];
    }
    __syncthreads();
    if (half==0){
      #pragma unroll
      for (int j=0;j<BPB;j++) x[j][o] = tanhf(a[j] + pA[o][j]);
    }
    __syncthreads();

    // ---- phase B: 6 gates, K split 0..95 / 96..191, 4-k register-blocked loads ----
    float p0[BPB], p1[BPB], p2[BPB], q0[BPB], q1[BPB], q2[BPB];
    #pragma unroll
    for (int j=0;j<BPB;j++){
      p0[j] = half ? 0.f : bi0; p1[j] = half ? 0.f : bi1; p2[j] = half ? 0.f : bi2;
      q0[j] = half ? 0.f : bh0; q1[j] = half ? 0.f : bh1; q2[j] = half ? 0.f : bh2;
    }
    const int kb = half*96;
    for (int kg=0; kg<96; kg+=4){
      const float* wbase = wPack + ((size_t)(kb+kg)*192 + o)*8;
      float4 wA[4], wB[4];
      #pragma unroll
      for (int u=0;u<4;u++){
        wA[u] = *(const float4*)(wbase + (size_t)u*192*8);
        wB[u] = *(const float4*)(wbase + (size_t)u*192*8 + 4);
      }
      const int k0 = kb+kg;
      #pragma unroll
      for (int j=0;j<BPB;j++){
        float4 xv = *(const float4*)&x[j][k0];
        float4 hv = *(const float4*)&h[j][k0];
        p0[j] += wA[0].x*xv.x + wA[1].x*xv.y + wA[2].x*xv.z + wA[3].x*xv.w;
        p1[j] += wA[0].y*xv.x + wA[1].y*xv.y + wA[2].y*xv.z + wA[3].y*xv.w;
        p2[j] += wA[0].z*xv.x + wA[1].z*xv.y + wA[2].z*xv.z + wA[3].z*xv.w;
        q0[j] += wA[0].w*hv.x + wA[1].w*hv.y + wA[2].w*hv.z + wA[3].w*hv.w;
        q1[j] += wB[0].x*hv.x + wB[1].x*hv.y + wB[2].x*hv.z + wB[3].x*hv.w;
        q2[j] += wB[0].y*hv.x + wB[1].y*hv.y + wB[2].y*hv.z + wB[3].y*hv.w;
      }
    }
    if (half==1){
      #pragma unroll
      for (int j=0;j<BPB;j++){
        pB[o][j*6+0]=p0[j]; pB[o][j*6+1]=p1[j]; pB[o][j*6+2]=p2[j];
        pB[o][j*6+3]=q0[j]; pB[o][j*6+4]=q1[j]; pB[o][j*6+5]=q2[j];
      }
    }
    __syncthreads();
    float pre[BPB];
    if (half==0){
      #pragma unroll
      for (int j=0;j<BPB;j++){
        float P0=p0[j]+pB[o][j*6+0], P1=p1[j]+pB[o][j*6+1], P2=p2[j]+pB[o][j*6+2];
        float Q0=q0[j]+pB[o][j*6+3], Q1=q1[j]+pB[o][j*6+4], Q2=q2[j]+pB[o][j*6+5];
        float rg = sigm(P0+Q0), z = sigm(P1+Q1);
        float n  = tanhf(P2 + rg*Q2);
        pre[j] = (1.f - z)*n + z*h[j][o];
        red1[j][o] = pre[j]; red2[j][o] = pre[j]*pre[j];
      }
    }
    __syncthreads();
    if (tid < 64){
      #pragma unroll
      for (int j=0;j<BPB;j++){
        float s0 = red1[j][tid]+red1[j][tid+64]+red1[j][tid+128];
        float q0r= red2[j][tid]+red2[j][tid+64]+red2[j][tid+128];
        #pragma unroll
        for (int off=32; off>0; off>>=1){ s0 += __shfl_down(s0,off); q0r += __shfl_down(q0r,off); }
        if (tid==0){ stL[j][0]=s0; stL[j][1]=q0r; }
      }
    }
    __syncthreads();
    if (half==0){
      const float inv = 1.f/192.f;
      #pragma unroll
      for (int j=0;j<BPB;j++){
        float mu = stL[j][0]*inv, var = stL[j][1]*inv - mu*mu;
        float hn = (pre[j]-mu)*rsqrtf(var+1e-5f)*w_ln + b_ln;
        h[j][o] = hn;
        red1[j][o] = hn*w_r0; red2[j][o] = hn*w_r1;
      }
    }
    __syncthreads();
    if (tid < 64){
      #pragma unroll
      for (int j=0;j<BPB;j++){
        float s0 = red1[j][tid]+red1[j][tid+64]+red1[j][tid+128];
        float q0r= red2[j][tid]+red2[j][tid+64]+red2[j][tid+128];
        #pragma unroll
        for (int off=32; off>0; off>>=1){ s0 += __shfl_down(s0,off); q0r += __shfl_down(q0r,off); }
        if (tid==0){ stR[j][0]=s0; stR[j][1]=q0r; }
      }
    }
    __syncthreads();
    if (tid < 16){
      #pragma unroll
      for (int j=0;j<BPB;j++){
        float rho = 1.25f*sigm(stR[j][0]+fb0);
        float phi = PI_F*tanhf(stR[j][1]+fb1);
        float rc = rho*cosf(phi), rs = rho*sinf(phi);
        float re = c[j][tid], im = c[j][tid+16];
        float nre = rc*re - rs*im;
        float nim = rs*re + rc*im;
        c[j][tid] = nre; c[j][tid+16] = nim;
        float* ob = out + ((size_t)(bb+j)*WOUT_ + s)*D_;
        ob[tid] = nre; ob[tid+16] = nim;
      }
    }
    __syncthreads();
  }
}

// ---------------- host launch ----------------
extern "C" void kernel_launch(void* const* d_in, const int* in_sizes, int n_in,
                              void* d_out, int out_size, void* d_ws, size_t ws_size,
                              hipStream_t stream)
{
  const float* x_in     = (const float*)d_in[0];
  const float* inp_w    = (const float*)d_in[1];
  const float* inp_b    = (const float*)d_in[2];
  const float* b_dw_w   = (const float*)d_in[3];
  const float* b_dw_b   = (const float*)d_in[4];
  const float* b_ln_w   = (const float*)d_in[5];
  const float* b_ln_b   = (const float*)d_in[6];
  const float* b_pw1_w  = (const float*)d_in[7];
  const float* b_pw1_b  = (const float*)d_in[8];
  const float* b_grn_g  = (const float*)d_in[9];
  const float* b_grn_b  = (const float*)d_in[10];
  const float* b_pw2_w  = (const float*)d_in[11];
  const float* b_pw2_b  = (const float*)d_in[12];
  const float* out_ln_w = (const float*)d_in[13];
  const float* out_ln_b = (const float*)d_in[14];
  const float* fc_rp_w  = (const float*)d_in[15];
  const float* fc_rp_b  = (const float*)d_in[16];
  const float* fc_gain_w= (const float*)d_in[17];
  const float* fc_gain_b= (const float*)d_in[18];
  const float* roll_in_w= (const float*)d_in[19];
  const float* roll_in_b= (const float*)d_in[20];
  const float* gru_wih  = (const float*)d_in[21];
  const float* gru_whh  = (const float*)d_in[22];
  const float* gru_bih  = (const float*)d_in[23];
  const float* gru_bhh  = (const float*)d_in[24];
  const float* roll_ln_w= (const float*)d_in[25];
  const float* roll_ln_b= (const float*)d_in[26];
  const float* fc_rp_r_w= (const float*)d_in[27];
  const float* fc_rp_r_b= (const float*)d_in[28];
  float* out = (float*)d_out;

  // ---- adaptive chunking ----
  const size_t SMAL_FLOATS = 505920 + 4096;
  size_t ws_floats = ws_size / 4;
  int nchunk = 256;
  const int cand[9] = {1,2,4,8,16,32,64,128,256};
  for (int ci=0; ci<9; ci++){
    size_t Mc_try = (size_t)M_ / cand[ci];
    if (Mc_try*768 + SMAL_FLOATS <= ws_floats){ nchunk = cand[ci]; break; }
  }
  const int    Bc = B_ / nchunk;
  const size_t Mc = (size_t)Bc * Q_;

  float* ws    = (float*)d_ws;
  float* h_c   = ws;
  float* yln_c = h_c   + Mc*192;
  float* mid_c = yln_c + Mc*192;
  float* smal  = mid_c + Mc*384;

  float* feats_c = mid_c;
  float* y1_c    = mid_c;
  float* rpraw   = mid_c;                // Mc*64 (y1 dead by then)
  float* rp4_c   = mid_c + Mc*64;        // Mc*64 (float4-packed {rc,rs,g0,g1})

  float* scaleB = smal;                  // Bc*384 (reserve 98304)
  float* w_pad  = smal + 98304;          // 64*192
  float* b_pad  = w_pad + 12288;         // 64
  float* xpost  = b_pad + 64;            // B_*32
  float* hlast  = xpost + 8192;          // B_*192
  float* wT1    = hlast + 49152;         // 224*192
  float* wPack  = wT1 + 43008;           // 192*192*8

  // one-time weight prep
  pack_w_kernel<<<(64*192+255)/256, 256, 0, stream>>>(fc_rp_w, fc_rp_b, fc_gain_w, fc_gain_b, w_pad, b_pad);
  prep_rollout_kernel<<<(224*192+192*192+255)/256, 256, 0, stream>>>(roll_in_w, gru_wih, gru_whh, wT1, wPack);

  const int gmx = (int)(Mc/64);
  for (int ch=0; ch<nchunk; ch++){
    const float* x_c = x_in + (size_t)ch*Mc*D_;
    // 1. features + input projection
    feats_kernel<<<(int)((Mc*32+255)/256), 256, 0, stream>>>(x_c, feats_c, (int)Mc);
    gemm_t64<0><<<dim3(gmx, 3), 256, 0, stream>>>(feats_c, inp_w, inp_b,
                                                  h_c, nullptr, nullptr, H_, INCH_);
    // 2. ConvNeXt blocks
    for (int blk = 0; blk < 2; blk++){
      const float* dww = b_dw_w + blk*H_*9;     const float* dwb = b_dw_b + blk*H_;
      const float* lnw = b_ln_w + blk*H_;       const float* lnb = b_ln_b + blk*H_;
      const float* p1w = b_pw1_w + blk*HID_*H_; const float* p1b = b_pw1_b + blk*HID_;
      const float* gg  = b_grn_g + blk*HID_;    const float* gb  = b_grn_b + blk*HID_;
      const float* p2w = b_pw2_w + blk*H_*HID_; const float* p2b = b_pw2_b + blk*H_;
      dwconv_ln4<<<(int)(Mc/4), 192, 0, stream>>>(h_c, dww, dwb, lnw, lnb, yln_c);
      gemm_t64<1><<<dim3(gmx, 6), 256, 0, stream>>>(yln_c, p1w, p1b,
                                                    y1_c, nullptr, nullptr, HID_, H_);
      grn_stats_kernel<<<Bc, 384, 0, stream>>>(y1_c, gg, scaleB);
      gemm_t64<2><<<dim3(gmx, 3), 256, 0, stream>>>(y1_c, p2w, p2b,
                                                    h_c, scaleB, gb, H_, HID_);
    }
    // 3. output LN -> h_seq, save last-t rows
    out_ln_kernel<<<(int)Mc, 192, 0, stream>>>(h_c, out_ln_w, out_ln_b, yln_c, hlast, ch*Bc);
    // 4. Kalman projection + float4-packed prep + batched-load scan
    gemm_t64<0><<<dim3(gmx, 1), 256, 0, stream>>>(yln_c, w_pad, b_pad,
                                                  rpraw, nullptr, nullptr, 64, H_);
    kalman_prep_kernel<<<(int)((Mc*16+255)/256), 256, 0, stream>>>(rpraw, rp4_c, (int)Mc);
    kalman_scan_kernel<<<(Bc+3)/4, 64, 0, stream>>>(x_c, rp4_c, xpost, ch*Bc, Bc);
  }
  // 5. GRU rollout (128 blocks, BPB=2, split-K, 4-k register-blocked loads)
  rollout_kernel<<<B_/BPB, RT_, 0, stream>>>(hlast, xpost, wT1, roll_in_b, wPack,
                                             gru_bih, gru_bhh, roll_ln_w, roll_ln_b,
                                             fc_rp_r_w, fc_rp_r_b, out);
  (void)in_sizes; (void)n_in; (void)out_size; (void)ws_size;
}

// Round 11
// 3444.743 us; speedup vs baseline: 1.4506x; 1.4506x over previous
//
#include <hip/hip_runtime.h>
#include <cstdint>
#include <cstddef>

#define B_    256
#define Q_    512
#define D_    32
#define H_    192
#define HID_  384
#define INCH_ 96
#define M_    (B_*Q_)    // 131072
#define WOUT_ 64
#define BPB   2          // batches per rollout block (2 -> 128 blocks)
#define PI_F  3.14159265358979323846f

typedef unsigned int uint_t;

__device__ __forceinline__ float sigm(float x){ return 1.f/(1.f+expf(-x)); }
__device__ __forceinline__ float gelu_exact(float x){ return 0.5f*x*(1.f+erff(x*0.7071067811865475f)); }

// ---------------- features: [x, dy, ddy] ----------------
__global__ void feats_kernel(const float* __restrict__ x, float* __restrict__ feats, int nrows){
  int idx = blockIdx.x*256 + threadIdx.x;
  if (idx >= nrows*32) return;
  int d  = idx & 31;
  int bt = idx >> 5;
  int t  = bt & 511;
  const float* xr = x + (size_t)bt*D_;
  float xc  = xr[d];
  float xm1 = (t>0) ? xr[d - D_]   : 0.f;
  float xm2 = (t>1) ? xr[d - 2*D_] : 0.f;
  float dy   = (t>0) ? xc - xm1   : 0.f;
  float dym1 = (t>1) ? xm1 - xm2  : 0.f;
  float ddy  = (t>0) ? dy - dym1  : 0.f;
  float* fr = feats + (size_t)bt*INCH_;
  fr[d] = xc; fr[D_+d] = dy; fr[2*D_+d] = ddy;
}

// ---------------- 64x64x8 fp32 tiled GEMM, 4 blocks/CU ----------------
// MODE 0: out = acc+bias ; MODE 1: out = gelu(acc+bias) ; MODE 2: A affine, C += acc+bias
template<int MODE>
__global__ __launch_bounds__(256,4) void gemm_t64(
    const float* __restrict__ Af,
    const float* __restrict__ W,  const float* __restrict__ bias,
    float* __restrict__ Cf,
    const float* __restrict__ scale, const float* __restrict__ grnb,
    int N, int K)
{
  __shared__ float As[8][64];
  __shared__ float Bs[8][64];
  const int tid = threadIdx.x;
  const int bm = blockIdx.x*64, bn = blockIdx.y*64;
  const int tx = tid & 15, ty = tid >> 4;
  const int lrow = (tid & 127) >> 1, lk = (tid & 1)*4;
  const bool isA = tid < 128;
  const float* srow = (MODE==2) ? (scale + (size_t)(bm>>9)*HID_) : nullptr;

  float acc[4][4];
  #pragma unroll
  for (int i=0;i<4;i++)
    #pragma unroll
    for (int j=0;j<4;j++) acc[i][j]=0.f;

  const float* gsrc = isA ? (Af + (size_t)(bm+lrow)*K) : (W + (size_t)(bn+lrow)*K);

  for (int k0=0;k0<K;k0+=8){
    float4 v = *(const float4*)(gsrc + k0 + lk);
    if (MODE==2 && isA){
      int c = k0+lk;
      float4 sc = *(const float4*)(srow+c);
      float4 gb = *(const float4*)(grnb+c);
      v.x = v.x*sc.x+gb.x; v.y = v.y*sc.y+gb.y;
      v.z = v.z*sc.z+gb.z; v.w = v.w*sc.w+gb.w;
    }
    if (isA){
      As[lk+0][lrow]=v.x; As[lk+1][lrow]=v.y; As[lk+2][lrow]=v.z; As[lk+3][lrow]=v.w;
    } else {
      Bs[lk+0][lrow]=v.x; Bs[lk+1][lrow]=v.y; Bs[lk+2][lrow]=v.z; Bs[lk+3][lrow]=v.w;
    }
    __syncthreads();
    #pragma unroll
    for (int kk=0;kk<8;kk++){
      float4 a = *(const float4*)&As[kk][ty*4];
      float4 b = *(const float4*)&Bs[kk][tx*4];
      float ar[4] = {a.x,a.y,a.z,a.w};
      #pragma unroll
      for (int i=0;i<4;i++){
        acc[i][0] += ar[i]*b.x; acc[i][1] += ar[i]*b.y;
        acc[i][2] += ar[i]*b.z; acc[i][3] += ar[i]*b.w;
      }
    }
    __syncthreads();
  }

  const int o0 = bn + tx*4;
  float4 b0 = *(const float4*)(bias + o0);
  #pragma unroll
  for (int i=0;i<4;i++){
    int m = bm + ty*4 + i;
    if (MODE==0){
      float4 v; v.x=acc[i][0]+b0.x; v.y=acc[i][1]+b0.y; v.z=acc[i][2]+b0.z; v.w=acc[i][3]+b0.w;
      *(float4*)(Cf + (size_t)m*N + o0) = v;
    } else if (MODE==1){
      float4 v;
      v.x = gelu_exact(acc[i][0]+b0.x); v.y = gelu_exact(acc[i][1]+b0.y);
      v.z = gelu_exact(acc[i][2]+b0.z); v.w = gelu_exact(acc[i][3]+b0.w);
      *(float4*)(Cf + (size_t)m*N + o0) = v;
    } else {
      float4 old = *(const float4*)(Cf + (size_t)m*N + o0);
      float4 v; v.x=old.x+acc[i][0]+b0.x; v.y=old.y+acc[i][1]+b0.y;
      v.z=old.z+acc[i][2]+b0.z; v.w=old.w+acc[i][3]+b0.w;
      *(float4*)(Cf + (size_t)m*N + o0) = v;
    }
  }
}

// ---------------- depthwise conv (k=9, edge pad) + LN, 4 timesteps per block ----------------
__global__ __launch_bounds__(192) void dwconv_ln4(
  const float* __restrict__ h, const float* __restrict__ dww, const float* __restrict__ dwb,
  const float* __restrict__ lnw, const float* __restrict__ lnb, float* __restrict__ yln)
{
  __shared__ float sh[12][192];
  __shared__ float rs_[192], rq_[192], st[2];
  const int c  = threadIdx.x;
  const int t0 = (blockIdx.x & 127) * 4;
  const size_t base = (size_t)(blockIdx.x >> 7) * Q_ * H_;
  #pragma unroll
  for (int r=0;r<12;r++){
    int tt = t0 - 4 + r; tt = tt<0?0:(tt>511?511:tt);
    sh[r][c] = h[base + (size_t)tt*H_ + c];
  }
  float w[9];
  #pragma unroll
  for (int k=0;k<9;k++) w[k] = dww[c*9+k];
  const float dbias = dwb[c], lw = lnw[c], lb = lnb[c];
  __syncthreads();
  for (int i=0;i<4;i++){
    float acc = dbias;
    #pragma unroll
    for (int k=0;k<9;k++) acc += w[k]*sh[i+k][c];
    rs_[c]=acc; rq_[c]=acc*acc;
    __syncthreads();
    if (c < 64){
      float s = rs_[c]+rs_[c+64]+rs_[c+128];
      float q = rq_[c]+rq_[c+64]+rq_[c+128];
      #pragma unroll
      for (int off=32; off>0; off>>=1){ s += __shfl_down(s,off); q += __shfl_down(q,off); }
      if (c==0){ st[0]=s; st[1]=q; }
    }
    __syncthreads();
    float mean = st[0]*(1.f/H_);
    float var  = st[1]*(1.f/H_) - mean*mean;
    float r = rsqrtf(var + 1e-5f);
    yln[base + (size_t)(t0+i)*H_ + c] = (acc-mean)*r*lw + lb;
  }
}

// ---------------- output LayerNorm (+ save last-timestep row) ----------------
__global__ __launch_bounds__(192) void out_ln_kernel(
  const float* __restrict__ h, const float* __restrict__ lnw, const float* __restrict__ lnb,
  float* __restrict__ o, float* __restrict__ hlast, int b0)
{
  __shared__ float rs_[192], rq_[192], st[2];
  const int c  = threadIdx.x;
  const int bt = blockIdx.x;
  float v = h[(size_t)bt*H_ + c];
  rs_[c]=v; rq_[c]=v*v;
  __syncthreads();
  if (c < 64){
    float s = rs_[c]+rs_[c+64]+rs_[c+128];
    float q = rq_[c]+rq_[c+64]+rq_[c+128];
    #pragma unroll
    for (int off=32; off>0; off>>=1){ s += __shfl_down(s,off); q += __shfl_down(q,off); }
    if (c==0){ st[0]=s; st[1]=q; }
  }
  __syncthreads();
  float mean = st[0]*(1.f/H_);
  float var  = st[1]*(1.f/H_) - mean*mean;
  float r = rsqrtf(var + 1e-5f);
  float res = (v-mean)*r*lnw[c] + lnb[c];
  o[(size_t)bt*H_ + c] = res;
  if ((bt & 511) == 511) hlast[(size_t)(b0 + (bt>>9))*H_ + c] = res;
}

// ---------------- GRN stats ----------------
__global__ __launch_bounds__(384) void grn_stats_kernel(
  const float* __restrict__ y1, const float* __restrict__ grn_g, float* __restrict__ scale)
{
  __shared__ float r[384];
  const int c = threadIdx.x;
  const int b = blockIdx.x;
  const float* p = y1 + (size_t)b*Q_*HID_ + c;
  float s = 0.f;
  #pragma unroll 8
  for (int t=0;t<Q_;t++){ float v = p[(size_t)t*HID_]; s += v*v; }
  float gx = sqrtf(s);
  r[c] = gx;
  __syncthreads();
  if (c < 64){
    float v = r[c]+r[c+64]+r[c+128]+r[c+192]+r[c+256]+r[c+320];
    #pragma unroll
    for (int off=32; off>0; off>>=1) v += __shfl_down(v,off);
    if (c==0) r[0]=v;
  }
  __syncthreads();
  float mean = r[0]*(1.f/HID_);
  scale[(size_t)b*HID_ + c] = 1.f + grn_g[c]*gx/(mean + 1e-6f);
}

// ---------------- pack fc_rp / fc_gain into padded (64,192) W ----------------
__global__ void pack_w_kernel(const float* __restrict__ frw, const float* __restrict__ frb,
                              const float* __restrict__ fgw, const float* __restrict__ fgb,
                              float* __restrict__ w_pad, float* __restrict__ b_pad)
{
  int idx = blockIdx.x*256 + threadIdx.x;
  if (idx >= 64*192) return;
  int o = idx / 192, k = idx % 192;
  float v = 0.f;
  if (o < 2) v = frw[o*192+k]; else if (o < 34) v = fgw[(o-2)*192+k];
  w_pad[idx] = v;
  if (k == 0){
    float bv = 0.f;
    if (o < 2) bv = frb[o]; else if (o < 34) bv = fgb[o-2];
    b_pad[o] = bv;
  }
}

// ---------------- wide Kalman prep: raw (Mc,64) -> rp4 (Mc,16) float4 {rc,rs,g0,g1} ----------------
__global__ void kalman_prep_kernel(const float* __restrict__ raw, float* __restrict__ rp4, int nrows){
  int idx = blockIdx.x*256 + threadIdx.x;
  if (idx >= nrows*16) return;
  int m  = idx & 15;
  int bt = idx >> 4;
  const float* r = raw + (size_t)bt*64;
  float rho = 1.25f*sigm(r[0]);
  float phi = PI_F * tanhf(r[1]);
  float4 v;
  v.x = rho*cosf(phi);
  v.y = rho*sinf(phi);
  v.z = sigm(r[2+m]);
  v.w = sigm(r[18+m]);
  *(float4*)(rp4 + (size_t)idx*4) = v;
}

// ---------------- sequential Kalman scan — 4-t register blocks, loads batched ----------------
__global__ __launch_bounds__(64) void kalman_scan_kernel(
  const float* __restrict__ x_c, const float* __restrict__ rp4, float* __restrict__ xpost,
  int b0, int Bc)
{
  const int lane = threadIdx.x;
  const int bl = blockIdx.x*4 + (lane>>4);
  if (bl >= Bc) return;
  const int m = lane & 15;
  const float* xb = x_c + (size_t)bl*Q_*D_;
  const float4* rb = (const float4*)rp4 + (size_t)bl*Q_*16 + m;
  float re = xb[m], im = xb[16+m];
  for (int t=0;t<Q_;t+=4){
    float4 w0 = rb[(size_t)(t+0)*16];
    float4 w1 = rb[(size_t)(t+1)*16];
    float4 w2 = rb[(size_t)(t+2)*16];
    float4 w3 = rb[(size_t)(t+3)*16];
    float y00 = xb[(size_t)(t+0)*D_ + m], y01 = xb[(size_t)(t+0)*D_ + 16 + m];
    float y10 = xb[(size_t)(t+1)*D_ + m], y11 = xb[(size_t)(t+1)*D_ + 16 + m];
    float y20 = xb[(size_t)(t+2)*D_ + m], y21 = xb[(size_t)(t+2)*D_ + 16 + m];
    float y30 = xb[(size_t)(t+3)*D_ + m], y31 = xb[(size_t)(t+3)*D_ + 16 + m];
    float pr, pi;
    pr = w0.x*re - w0.y*im; pi = w0.y*re + w0.x*im;
    re = pr + w0.z*(y00 - pr); im = pi + w0.w*(y01 - pi);
    pr = w1.x*re - w1.y*im; pi = w1.y*re + w1.x*im;
    re = pr + w1.z*(y10 - pr); im = pi + w1.w*(y11 - pi);
    pr = w2.x*re - w2.y*im; pi = w2.y*re + w2.x*im;
    re = pr + w2.z*(y20 - pr); im = pi + w2.w*(y21 - pi);
    pr = w3.x*re - w3.y*im; pi = w3.y*re + w3.x*im;
    re = pr + w3.z*(y30 - pr); im = pi + w3.w*(y31 - pi);
  }
  xpost[(b0+bl)*D_ + m] = re;
  xpost[(b0+bl)*D_ + 16 + m] = im;
}

// ---------------- rollout weight prep: wT1[k][o] + packed [k][o][8] gate block ----------------
__global__ void prep_rollout_kernel(const float* __restrict__ riw, const float* __restrict__ wih,
                                    const float* __restrict__ whh,
                                    float* __restrict__ wT1, float* __restrict__ wPack)
{
  int idx = blockIdx.x*256 + threadIdx.x;
  if (idx < 224*192){
    int o = idx % 192, k = idx / 192;
    wT1[idx] = riw[o*224 + k];
    return;
  }
  idx -= 224*192;
  if (idx < 192*192){
    int o = idx % 192, k = idx / 192;
    float* w = wPack + ((size_t)k*192 + o)*8;
    w[0] = wih[(0*192+o)*192 + k];
    w[1] = wih[(1*192+o)*192 + k];
    w[2] = wih[(2*192+o)*192 + k];
    w[3] = whh[(0*192+o)*192 + k];
    w[4] = whh[(1*192+o)*192 + k];
    w[5] = whh[(2*192+o)*192 + k];
    w[6] = 0.f; w[7] = 0.f;
  }
}

// ---------------- GRU rollout: 192 threads (3 waves), BPB=2, NO split-K,
// ---------------- register-blocked loads sized for the 128-VGPR budget ----------------
__global__ __launch_bounds__(192, 1) void rollout_kernel(
  const float* __restrict__ hlast, const float* __restrict__ xpost,
  const float* __restrict__ wT1,  const float* __restrict__ rib_,
  const float* __restrict__ wPack,
  const float* __restrict__ bih,  const float* __restrict__ bhh,
  const float* __restrict__ lnw,  const float* __restrict__ lnb,
  const float* __restrict__ frw,  const float* __restrict__ frb,
  float* __restrict__ out)
{
  const int o  = threadIdx.x;      // 0..191, one output channel per thread
  const int bb = blockIdx.x*BPB;
  __shared__ float h[BPB][192], x[BPB][192], c[BPB][32];
  __shared__ float red1[BPB][192], red2[BPB][192];
  __shared__ float stL[BPB][2], stR[BPB][2];

  #pragma unroll
  for (int j=0;j<BPB;j++) h[j][o] = hlast[(size_t)(bb+j)*H_ + o];
  if (o < 32){
    #pragma unroll
    for (int j=0;j<BPB;j++) c[j][o] = xpost[(bb+j)*D_ + o];
  }
  const float w_ln = lnw[o], b_ln = lnb[o];
  const float w_r0 = frw[o], w_r1 = frw[192+o];
  const float fb0 = frb[0], fb1 = frb[1];
  const float bi0 = bih[o], bi1 = bih[192+o], bi2 = bih[384+o];
  const float bh0 = bhh[o], bh1 = bhh[192+o], bh2 = bhh[384+o];
  const float rib = rib_[o];
  __syncthreads();

  for (int s=0; s<WOUT_; s++){
    // ---- phase A: x = tanh(W1 @ [h; c] + b1), full K per thread, 8-k groups ----
    float a[BPB];
    #pragma unroll
    for (int j=0;j<BPB;j++) a[j] = rib;
    for (int kg=0; kg<192; kg+=8){
      float w[8];
      #pragma unroll
      for (int u=0;u<8;u++) w[u] = wT1[(kg+u)*192+o];
      #pragma unroll
      for (int u=0;u<8;u+=4){
        #pragma unroll
        for (int j=0;j<BPB;j++){
          float4 hv = *(const float4*)&h[j][kg+u];
          a[j] += w[u]*hv.x + w[u+1]*hv.y + w[u+2]*hv.z + w[u+3]*hv.w;
        }
      }
    }
    {
      float w[8];
      #pragma unroll
      for (int kg=0; kg<32; kg+=8){
        #pragma unroll
        for (int u=0;u<8;u++) w[u] = wT1[(192+kg+u)*192+o];
        #pragma unroll
        for (int u=0;u<8;u+=4){
          #pragma unroll
          for (int j=0;j<BPB;j++){
            float4 cv = *(const float4*)&c[j][kg+u];
            a[j] += w[u]*cv.x + w[u+1]*cv.y + w[u+2]*cv.z + w[u+3]*cv.w;
          }
        }
      }
    }
    #pragma unroll
    for (int j=0;j<BPB;j++) x[j][o] = tanhf(a[j]);
    __syncthreads();

    // ---- phase B: 6 gates, full 192 K per thread, 4-k register-blocked loads ----
    float p0[BPB], p1[BPB], p2[BPB], q0[BPB], q1[BPB], q2[BPB];
    #pragma unroll
    for (int j=0;j<BPB;j++){ p0[j]=bi0; p1[j]=bi1; p2[j]=bi2; q0[j]=bh0; q1[j]=bh1; q2[j]=bh2; }
    for (int kg=0; kg<192; kg+=4){
      const float* wbase = wPack + ((size_t)kg*192 + o)*8;
      float4 wA[4], wB[4];
      #pragma unroll
      for (int u=0;u<4;u++){
        wA[u] = *(const float4*)(wbase + (size_t)u*192*8);
        wB[u] = *(const float4*)(wbase + (size_t)u*192*8 + 4);
      }
      #pragma unroll
      for (int j=0;j<BPB;j++){
        float4 xv = *(const float4*)&x[j][kg];
        float4 hv = *(const float4*)&h[j][kg];
        p0[j] += wA[0].x*xv.x + wA[1].x*xv.y + wA[2].x*xv.z + wA[3].x*xv.w;
        p1[j] += wA[0].y*xv.x + wA[1].y*xv.y + wA[2].y*xv.z + wA[3].y*xv.w;
        p2[j] += wA[0].z*xv.x + wA[1].z*xv.y + wA[2].z*xv.z + wA[3].z*xv.w;
        q0[j] += wA[0].w*hv.x + wA[1].w*hv.y + wA[2].w*hv.z + wA[3].w*hv.w;
        q1[j] += wB[0].x*hv.x + wB[1].x*hv.y + wB[2].x*hv.z + wB[3].x*hv.w;
        q2[j] += wB[0].y*hv.x + wB[1].y*hv.y + wB[2].y*hv.z + wB[3].y*hv.w;
      }
    }
    float pre[BPB];
    #pragma unroll
    for (int j=0;j<BPB;j++){
      float rg = sigm(p0[j]+q0[j]), z = sigm(p1[j]+q1[j]);
      float n  = tanhf(p2[j] + rg*q2[j]);
      pre[j] = (1.f - z)*n + z*h[j][o];
      red1[j][o] = pre[j]; red2[j][o] = pre[j]*pre[j];
    }
    __syncthreads();
    if (o < 64){
      #pragma unroll
      for (int j=0;j<BPB;j++){
        float s0 = red1[j][o]+red1[j][o+64]+red1[j][o+128];
        float q0r= red2[j][o]+red2[j][o+64]+red2[j][o+128];
        #pragma unroll
        for (int off=32; off>0; off>>=1){ s0 += __shfl_down(s0,off); q0r += __shfl_down(q0r,off); }
        if (o==0){ stL[j][0]=s0; stL[j][1]=q0r; }
      }
    }
    __syncthreads();
    {
      const float inv = 1.f/192.f;
      #pragma unroll
      for (int j=0;j<BPB;j++){
        float mu = stL[j][0]*inv, var = stL[j][1]*inv - mu*mu;
        float hn = (pre[j]-mu)*rsqrtf(var+1e-5f)*w_ln + b_ln;
        h[j][o] = hn;
        red1[j][o] = hn*w_r0; red2[j][o] = hn*w_r1;
      }
    }
    __syncthreads();
    if (o < 64){
      #pragma unroll
      for (int j=0;j<BPB;j++){
        float s0 = red1[j][o]+red1[j][o+64]+red1[j][o+128];
        float q0r= red2[j][o]+red2[j][o+64]+red2[j][o+128];
        #pragma unroll
        for (int off=32; off>0; off>>=1){ s0 += __shfl_down(s0,off); q0r += __shfl_down(q0r,off); }
        if (o==0){ stR[j][0]=s0; stR[j][1]=q0r; }
      }
    }
    __syncthreads();
    if (o < 16){
      #pragma unroll
      for (int j=0;j<BPB;j++){
        float rho = 1.25f*sigm(stR[j][0]+fb0);
        float phi = PI_F*tanhf(stR[j][1]+fb1);
        float rc = rho*cosf(phi), rs = rho*sinf(phi);
        float re = c[j][o], im = c[j][o+16];
        float nre = rc*re - rs*im;
        float nim = rs*re + rc*im;
        c[j][o] = nre; c[j][o+16] = nim;
        float* ob = out + ((size_t)(bb+j)*WOUT_ + s)*D_;
        ob[o] = nre; ob[o+16] = nim;
      }
    }
    __syncthreads();
  }
}

// ---------------- host launch ----------------
extern "C" void kernel_launch(void* const* d_in, const int* in_sizes, int n_in,
                              void* d_out, int out_size, void* d_ws, size_t ws_size,
                              hipStream_t stream)
{
  const float* x_in     = (const float*)d_in[0];
  const float* inp_w    = (const float*)d_in[1];
  const float* inp_b    = (const float*)d_in[2];
  const float* b_dw_w   = (const float*)d_in[3];
  const float* b_dw_b   = (const float*)d_in[4];
  const float* b_ln_w   = (const float*)d_in[5];
  const float* b_ln_b   = (const float*)d_in[6];
  const float* b_pw1_w  = (const float*)d_in[7];
  const float* b_pw1_b  = (const float*)d_in[8];
  const float* b_grn_g  = (const float*)d_in[9];
  const float* b_grn_b  = (const float*)d_in[10];
  const float* b_pw2_w  = (const float*)d_in[11];
  const float* b_pw2_b  = (const float*)d_in[12];
  const float* out_ln_w = (const float*)d_in[13];
  const float* out_ln_b = (const float*)d_in[14];
  const float* fc_rp_w  = (const float*)d_in[15];
  const float* fc_rp_b  = (const float*)d_in[16];
  const float* fc_gain_w= (const float*)d_in[17];
  const float* fc_gain_b= (const float*)d_in[18];
  const float* roll_in_w= (const float*)d_in[19];
  const float* roll_in_b= (const float*)d_in[20];
  const float* gru_wih  = (const float*)d_in[21];
  const float* gru_whh  = (const float*)d_in[22];
  const float* gru_bih  = (const float*)d_in[23];
  const float* gru_bhh  = (const float*)d_in[24];
  const float* roll_ln_w= (const float*)d_in[25];
  const float* roll_ln_b= (const float*)d_in[26];
  const float* fc_rp_r_w= (const float*)d_in[27];
  const float* fc_rp_r_b= (const float*)d_in[28];
  float* out = (float*)d_out;

  // ---- adaptive chunking ----
  const size_t SMAL_FLOATS = 505920 + 4096;
  size_t ws_floats = ws_size / 4;
  int nchunk = 256;
  const int cand[9] = {1,2,4,8,16,32,64,128,256};
  for (int ci=0; ci<9; ci++){
    size_t Mc_try = (size_t)M_ / cand[ci];
    if (Mc_try*768 + SMAL_FLOATS <= ws_floats){ nchunk = cand[ci]; break; }
  }
  const int    Bc = B_ / nchunk;
  const size_t Mc = (size_t)Bc * Q_;

  float* ws    = (float*)d_ws;
  float* h_c   = ws;
  float* yln_c = h_c   + Mc*192;
  float* mid_c = yln_c + Mc*192;
  float* smal  = mid_c + Mc*384;

  float* feats_c = mid_c;
  float* y1_c    = mid_c;
  float* rpraw   = mid_c;                // Mc*64 (y1 dead by then)
  float* rp4_c   = mid_c + Mc*64;        // Mc*64 (float4-packed {rc,rs,g0,g1})

  float* scaleB = smal;                  // Bc*384 (reserve 98304)
  float* w_pad  = smal + 98304;          // 64*192
  float* b_pad  = w_pad + 12288;         // 64
  float* xpost  = b_pad + 64;            // B_*32
  float* hlast  = xpost + 8192;          // B_*192
  float* wT1    = hlast + 49152;         // 224*192
  float* wPack  = wT1 + 43008;           // 192*192*8

  // one-time weight prep
  pack_w_kernel<<<(64*192+255)/256, 256, 0, stream>>>(fc_rp_w, fc_rp_b, fc_gain_w, fc_gain_b, w_pad, b_pad);
  prep_rollout_kernel<<<(224*192+192*192+255)/256, 256, 0, stream>>>(roll_in_w, gru_wih, gru_whh, wT1, wPack);

  const int gmx = (int)(Mc/64);
  for (int ch=0; ch<nchunk; ch++){
    const float* x_c = x_in + (size_t)ch*Mc*D_;
    // 1. features + input projection
    feats_kernel<<<(int)((Mc*32+255)/256), 256, 0, stream>>>(x_c, feats_c, (int)Mc);
    gemm_t64<0><<<dim3(gmx, 3), 256, 0, stream>>>(feats_c, inp_w, inp_b,
                                                  h_c, nullptr, nullptr, H_, INCH_);
    // 2. ConvNeXt blocks
    for (int blk = 0; blk < 2; blk++){
      const float* dww = b_dw_w + blk*H_*9;     const float* dwb = b_dw_b + blk*H_;
      const float* lnw = b_ln_w + blk*H_;       const float* lnb = b_ln_b + blk*H_;
      const float* p1w = b_pw1_w + blk*HID_*H_; const float* p1b = b_pw1_b + blk*HID_;
      const float* gg  = b_grn_g + blk*HID_;    const float* gb  = b_grn_b + blk*HID_;
      const float* p2w = b_pw2_w + blk*H_*HID_; const float* p2b = b_pw2_b + blk*H_;
      dwconv_ln4<<<(int)(Mc/4), 192, 0, stream>>>(h_c, dww, dwb, lnw, lnb, yln_c);
      gemm_t64<1><<<dim3(gmx, 6), 256, 0, stream>>>(yln_c, p1w, p1b,
                                                    y1_c, nullptr, nullptr, HID_, H_);
      grn_stats_kernel<<<Bc, 384, 0, stream>>>(y1_c, gg, scaleB);
      gemm_t64<2><<<dim3(gmx, 3), 256, 0, stream>>>(y1_c, p2w, p2b,
                                                    h_c, scaleB, gb, H_, HID_);
    }
    // 3. output LN -> h_seq, save last-t rows
    out_ln_kernel<<<(int)Mc, 192, 0, stream>>>(h_c, out_ln_w, out_ln_b, yln_c, hlast, ch*Bc);
    // 4. Kalman projection + float4-packed prep + batched-load scan
    gemm_t64<0><<<dim3(gmx, 1), 256, 0, stream>>>(yln_c, w_pad, b_pad,
                                                  rpraw, nullptr, nullptr, 64, H_);
    kalman_prep_kernel<<<(int)((Mc*16+255)/256), 256, 0, stream>>>(rpraw, rp4_c, (int)Mc);
    kalman_scan_kernel<<<(Bc+3)/4, 64, 0, stream>>>(x_c, rp4_c, xpost, ch*Bc, Bc);
  }
  // 5. GRU rollout (128 blocks, 192 threads, BPB=2, no split-K, 4-k register blocks)
  rollout_kernel<<<B_/BPB, 192, 0, stream>>>(hlast, xpost, wT1, roll_in_b, wPack,
                                             gru_bih, gru_bhh, roll_ln_w, roll_ln_b,
                                             fc_rp_r_w, fc_rp_r_b, out);
  (void)in_sizes; (void)n_in; (void)out_size; (void)ws_size;
}